// Round 1
// baseline (527.834 us; speedup 1.0000x reference)
//
#include <hip/hip_runtime.h>
#include <math.h>

#define EPSF 1e-12f

// ---------------- block reduce (256 threads, wave64) ----------------
__device__ __forceinline__ float block_reduce_sum_256(float v) {
#pragma unroll
  for (int o = 32; o > 0; o >>= 1) v += __shfl_down(v, o, 64);
  __shared__ float ws4[4];
  const int lane = threadIdx.x & 63;
  const int w = threadIdx.x >> 6;
  if (lane == 0) ws4[w] = v;
  __syncthreads();
  if (threadIdx.x == 0) ws4[0] = ws4[0] + ws4[1] + ws4[2] + ws4[3];
  __syncthreads();
  return ws4[0];
}

// ---------------- stage 1: src readout [4096,512] ----------------
__global__ __launch_bounds__(256) void k_src_readout(const float* __restrict__ m,
                                                     const int* __restrict__ src_mask,
                                                     float* __restrict__ srcR) {
  const int b = blockIdx.x;
  __shared__ int msk[32];
  __shared__ float s_inv;
  const int tid = threadIdx.x;
  if (tid < 32) msk[tid] = src_mask[b * 32 + tid];
  __syncthreads();
  if (tid == 0) {
    float c = 0.f;
    for (int s = 0; s < 32; ++s) c += (float)msk[s];
    s_inv = 1.0f / fmaxf(c, EPSF);
  }
  __syncthreads();
  const float inv = s_inv;
  const float* mb = m + (size_t)b * (32 * 512) + 2 * tid;
  float ax = 0.f, ay = 0.f;
  for (int s = 0; s < 32; ++s) {
    if (msk[s] != 0) {
      float2 v = *(const float2*)(mb + s * 512);
      ax += v.x;
      ay += v.y;
    }
  }
  float2 o;
  o.x = ax * inv;
  o.y = ay * inv;
  *(float2*)(srcR + (size_t)b * 512 + 2 * tid) = o;
}

// ---------------- stage 2: tgt readout [8192,512] ----------------
// grid (32, 4, 4) = (batch, t-tile of 64, d-tile of 128); block 256 = (tx32, ty8)
#define TR_LDW 257
__global__ __launch_bounds__(256) void k_tgt_readout(const float* __restrict__ om,
                                                     const int* __restrict__ tgt_mask,
                                                     float* __restrict__ tgtR) {
  const int b = blockIdx.x, tt = blockIdx.y, dt = blockIdx.z;
  const int t0 = tt * 64, d0 = dt * 128;
  __shared__ float wm[64 * TR_LDW];  // mask values as float, padded stride
  __shared__ float cpart[256];
  __shared__ float s_inv[64];
  const int tid = threadIdx.x;
  const int* mbase = tgt_mask + ((size_t)(b * 256 + t0)) * 256;
  for (int i = 0; i < 64; ++i) {
    int idx = tid + 256 * i;  // linear over 64x256 tile, coalesced
    wm[(idx >> 8) * TR_LDW + (idx & 255)] = (float)mbase[idx];
  }
  __syncthreads();
  {
    const int r = tid >> 2, q = tid & 3;
    float c = 0.f;
    for (int u = 0; u < 64; ++u) c += wm[r * TR_LDW + q * 64 + u];
    cpart[tid] = c;
  }
  __syncthreads();
  if (tid < 64) {
    float c = cpart[4 * tid] + cpart[4 * tid + 1] + cpart[4 * tid + 2] + cpart[4 * tid + 3];
    s_inv[tid] = 1.0f / fmaxf(c, EPSF);
  }
  __syncthreads();
  const int tx = tid & 31, ty = tid >> 5;
  float4 acc[8];
#pragma unroll
  for (int j = 0; j < 8; ++j) acc[j] = make_float4(0.f, 0.f, 0.f, 0.f);
  const float* ob = om + (size_t)b * 256 * 512 + d0 + tx * 4;
  for (int u = 0; u < 256; ++u) {
    float4 o = *(const float4*)(ob + (size_t)u * 512);
#pragma unroll
    for (int j = 0; j < 8; ++j) {
      float w = wm[(ty * 8 + j) * TR_LDW + u];
      acc[j].x += o.x * w;
      acc[j].y += o.y * w;
      acc[j].z += o.z * w;
      acc[j].w += o.w * w;
    }
  }
#pragma unroll
  for (int j = 0; j < 8; ++j) {
    const int t = ty * 8 + j;
    const float inv = s_inv[t];
    float4 r;
    r.x = acc[j].x * inv;
    r.y = acc[j].y * inv;
    r.z = acc[j].z * inv;
    r.w = acc[j].w * inv;
    *(float4*)(tgtR + ((size_t)(b * 256 + t0 + t)) * 512 + d0 + tx * 4) = r;
  }
}

// ---------------- stage 2b: row squared norms ----------------
__global__ __launch_bounds__(256) void k_rowsq(const float* __restrict__ X,
                                               float* __restrict__ sq) {
  const int r = blockIdx.x;
  const int tid = threadIdx.x;
  float2 v = *(const float2*)(X + (size_t)r * 512 + 2 * tid);
  float s = v.x * v.x + v.y * v.y;
  s = block_reduce_sum_256(s);
  if (tid == 0) sq[r] = s;
}

// ---------------- stage 3: cross GEMM + distance + exp ----------------
// C[M=8192, N=4096] over K=512. A=[M,K] tgtR, B=[N,K] srcR (NT).
// Block tile 128x128, BK=16, 256 threads, 8x8 per thread.
#define LDT 132  // padded LDS leading stride (floats)
__global__ __launch_bounds__(256) void k_cross(const float* __restrict__ A,
                                               const float* __restrict__ Bm,
                                               const float* __restrict__ tsq,
                                               const float* __restrict__ ssq,
                                               float* __restrict__ out) {
  __shared__ float As[16 * LDT];
  __shared__ float Bs[16 * LDT];
  const int tid = threadIdx.x;
  const int bn = blockIdx.x, bm = blockIdx.y;
  const int row0 = bm * 128, col0 = bn * 128;
  const int tx = tid & 15, ty = tid >> 4;

  float acc[8][8];
#pragma unroll
  for (int i = 0; i < 8; ++i)
#pragma unroll
    for (int j = 0; j < 8; ++j) acc[i][j] = 0.f;

  const int lr = tid >> 1;         // 0..127 : tile row
  const int lk = (tid & 1) * 8;    // 0 or 8 : k offset
  const float* ga = A + (size_t)(row0 + lr) * 512 + lk;
  const float* gb = Bm + (size_t)(col0 + lr) * 512 + lk;

  for (int kt = 0; kt < 32; ++kt) {
    float4 av0 = *(const float4*)(ga + kt * 16);
    float4 av1 = *(const float4*)(ga + kt * 16 + 4);
    float4 bv0 = *(const float4*)(gb + kt * 16);
    float4 bv1 = *(const float4*)(gb + kt * 16 + 4);
    __syncthreads();  // previous iteration's reads done before overwrite
    As[(lk + 0) * LDT + lr] = av0.x;
    As[(lk + 1) * LDT + lr] = av0.y;
    As[(lk + 2) * LDT + lr] = av0.z;
    As[(lk + 3) * LDT + lr] = av0.w;
    As[(lk + 4) * LDT + lr] = av1.x;
    As[(lk + 5) * LDT + lr] = av1.y;
    As[(lk + 6) * LDT + lr] = av1.z;
    As[(lk + 7) * LDT + lr] = av1.w;
    Bs[(lk + 0) * LDT + lr] = bv0.x;
    Bs[(lk + 1) * LDT + lr] = bv0.y;
    Bs[(lk + 2) * LDT + lr] = bv0.z;
    Bs[(lk + 3) * LDT + lr] = bv0.w;
    Bs[(lk + 4) * LDT + lr] = bv1.x;
    Bs[(lk + 5) * LDT + lr] = bv1.y;
    Bs[(lk + 6) * LDT + lr] = bv1.z;
    Bs[(lk + 7) * LDT + lr] = bv1.w;
    __syncthreads();
#pragma unroll
    for (int k = 0; k < 16; ++k) {
      float a[8], bb[8];
      *(float4*)&a[0] = *(const float4*)&As[k * LDT + ty * 4];
      *(float4*)&a[4] = *(const float4*)&As[k * LDT + 64 + ty * 4];
      *(float4*)&bb[0] = *(const float4*)&Bs[k * LDT + tx * 4];
      *(float4*)&bb[4] = *(const float4*)&Bs[k * LDT + 64 + tx * 4];
#pragma unroll
      for (int i = 0; i < 8; ++i)
#pragma unroll
        for (int j = 0; j < 8; ++j) acc[i][j] += a[i] * bb[j];
    }
  }

  // epilogue: d2 = t2 + s2 - 2c ; out = exp(-sqrt(max(d2,eps)))
  float ts[8], ss[8];
#pragma unroll
  for (int i = 0; i < 4; ++i) {
    ts[i] = tsq[row0 + ty * 4 + i];
    ts[i + 4] = tsq[row0 + 64 + ty * 4 + i];
    ss[i] = ssq[col0 + tx * 4 + i];
    ss[i + 4] = ssq[col0 + 64 + tx * 4 + i];
  }
#pragma unroll
  for (int i = 0; i < 8; ++i) {
    const int row = row0 + ((i < 4) ? (ty * 4 + i) : (64 + ty * 4 + (i - 4)));
    float4 o0, o1;
    {
      float d2, dd;
      d2 = ts[i] + ss[0] - 2.f * acc[i][0]; dd = sqrtf(fmaxf(d2, EPSF)); o0.x = expf(-dd);
      d2 = ts[i] + ss[1] - 2.f * acc[i][1]; dd = sqrtf(fmaxf(d2, EPSF)); o0.y = expf(-dd);
      d2 = ts[i] + ss[2] - 2.f * acc[i][2]; dd = sqrtf(fmaxf(d2, EPSF)); o0.z = expf(-dd);
      d2 = ts[i] + ss[3] - 2.f * acc[i][3]; dd = sqrtf(fmaxf(d2, EPSF)); o0.w = expf(-dd);
      d2 = ts[i] + ss[4] - 2.f * acc[i][4]; dd = sqrtf(fmaxf(d2, EPSF)); o1.x = expf(-dd);
      d2 = ts[i] + ss[5] - 2.f * acc[i][5]; dd = sqrtf(fmaxf(d2, EPSF)); o1.y = expf(-dd);
      d2 = ts[i] + ss[6] - 2.f * acc[i][6]; dd = sqrtf(fmaxf(d2, EPSF)); o1.z = expf(-dd);
      d2 = ts[i] + ss[7] - 2.f * acc[i][7]; dd = sqrtf(fmaxf(d2, EPSF)); o1.w = expf(-dd);
    }
    *(float4*)(out + (size_t)row * 4096 + col0 + tx * 4) = o0;
    *(float4*)(out + (size_t)row * 4096 + col0 + 64 + tx * 4) = o1;
  }
}

// ---------------- stage 4: row L1 normalize ----------------
__global__ __launch_bounds__(256) void k_norm(float* __restrict__ out) {
  const size_t base = (size_t)blockIdx.x * 4096;
  const int tid = threadIdx.x;
  float4 v[4];
  float s = 0.f;
#pragma unroll
  for (int i = 0; i < 4; ++i) {
    v[i] = *(const float4*)(out + base + (size_t)(tid + 256 * i) * 4);
    s += v[i].x + v[i].y + v[i].z + v[i].w;
  }
  s = block_reduce_sum_256(s);
  const float inv = 1.0f / fmaxf(s, EPSF);
#pragma unroll
  for (int i = 0; i < 4; ++i) {
    float4 r;
    r.x = v[i].x * inv;
    r.y = v[i].y * inv;
    r.z = v[i].z * inv;
    r.w = v[i].w * inv;
    *(float4*)(out + base + (size_t)(tid + 256 * i) * 4) = r;
  }
}

extern "C" void kernel_launch(void* const* d_in, const int* in_sizes, int n_in,
                              void* d_out, int out_size, void* d_ws, size_t ws_size,
                              hipStream_t stream) {
  const float* m = (const float*)d_in[0];        // [4096,32,512]
  const float* om = (const float*)d_in[1];       // [32,256,512]
  const int* src_mask = (const int*)d_in[2];     // [4096,1,32]
  const int* tgt_mask = (const int*)d_in[3];     // [32,256,256]
  float* out = (float*)d_out;                    // [32,256,4096]

  float* ws = (float*)d_ws;
  float* srcR = ws;                        // 4096*512
  float* tgtR = srcR + 4096 * 512;         // 8192*512
  float* ssq = tgtR + 8192 * 512;          // 4096
  float* tsq = ssq + 4096;                 // 8192

  k_src_readout<<<4096, 256, 0, stream>>>(m, src_mask, srcR);
  k_tgt_readout<<<dim3(32, 4, 4), 256, 0, stream>>>(om, tgt_mask, tgtR);
  k_rowsq<<<4096, 256, 0, stream>>>(srcR, ssq);
  k_rowsq<<<8192, 256, 0, stream>>>(tgtR, tsq);
  k_cross<<<dim3(32, 64), 256, 0, stream>>>(tgtR, srcR, tsq, ssq, out);
  k_norm<<<8192, 256, 0, stream>>>(out);
}

// Round 2
// 351.222 us; speedup vs baseline: 1.5028x; 1.5028x over previous
//
#include <hip/hip_runtime.h>
#include <math.h>

#define EPSF 1e-12f

typedef short bf16x8 __attribute__((ext_vector_type(8)));
typedef float f32x4 __attribute__((ext_vector_type(4)));

__device__ __forceinline__ void gload_lds16(const void* g, void* l) {
  __builtin_amdgcn_global_load_lds(
      (const __attribute__((address_space(1))) unsigned int*)g,
      (__attribute__((address_space(3))) unsigned int*)l, 16, 0, 0);
}

// ---------------- block reduce (256 threads, wave64) ----------------
__device__ __forceinline__ float block_reduce_sum_256(float v) {
#pragma unroll
  for (int o = 32; o > 0; o >>= 1) v += __shfl_down(v, o, 64);
  __shared__ float ws4[4];
  const int lane = threadIdx.x & 63;
  const int w = threadIdx.x >> 6;
  if (lane == 0) ws4[w] = v;
  __syncthreads();
  if (threadIdx.x == 0) ws4[0] = ws4[0] + ws4[1] + ws4[2] + ws4[3];
  __syncthreads();
  return ws4[0];
}

// ---------------- stage 1: src readout [4096,512] ----------------
__global__ __launch_bounds__(256) void k_src_readout(const float* __restrict__ m,
                                                     const int* __restrict__ src_mask,
                                                     float* __restrict__ srcR) {
  const int b = blockIdx.x;
  __shared__ int msk[32];
  __shared__ float s_inv;
  const int tid = threadIdx.x;
  if (tid < 32) msk[tid] = src_mask[b * 32 + tid];
  __syncthreads();
  if (tid == 0) {
    float c = 0.f;
    for (int s = 0; s < 32; ++s) c += (float)msk[s];
    s_inv = 1.0f / fmaxf(c, EPSF);
  }
  __syncthreads();
  const float inv = s_inv;
  const float* mb = m + (size_t)b * (32 * 512) + 2 * tid;
  float ax = 0.f, ay = 0.f;
  for (int s = 0; s < 32; ++s) {
    if (msk[s] != 0) {
      float2 v = *(const float2*)(mb + s * 512);
      ax += v.x;
      ay += v.y;
    }
  }
  float2 o;
  o.x = ax * inv;
  o.y = ay * inv;
  *(float2*)(srcR + (size_t)b * 512 + 2 * tid) = o;
}

// ---------------- stage 2: tgt readout [8192,512] ----------------
#define TR_LDW 257
__global__ __launch_bounds__(256) void k_tgt_readout(const float* __restrict__ om,
                                                     const int* __restrict__ tgt_mask,
                                                     float* __restrict__ tgtR) {
  const int b = blockIdx.x, tt = blockIdx.y, dt = blockIdx.z;
  const int t0 = tt * 64, d0 = dt * 128;
  __shared__ float wm[64 * TR_LDW];
  __shared__ float cpart[256];
  __shared__ float s_inv[64];
  const int tid = threadIdx.x;
  const int* mbase = tgt_mask + ((size_t)(b * 256 + t0)) * 256;
  for (int i = 0; i < 64; ++i) {
    int idx = tid + 256 * i;
    wm[(idx >> 8) * TR_LDW + (idx & 255)] = (float)mbase[idx];
  }
  __syncthreads();
  {
    const int r = tid >> 2, q = tid & 3;
    float c = 0.f;
    for (int u = 0; u < 64; ++u) c += wm[r * TR_LDW + q * 64 + u];
    cpart[tid] = c;
  }
  __syncthreads();
  if (tid < 64) {
    float c = cpart[4 * tid] + cpart[4 * tid + 1] + cpart[4 * tid + 2] + cpart[4 * tid + 3];
    s_inv[tid] = 1.0f / fmaxf(c, EPSF);
  }
  __syncthreads();
  const int tx = tid & 31, ty = tid >> 5;
  float4 acc[8];
#pragma unroll
  for (int j = 0; j < 8; ++j) acc[j] = make_float4(0.f, 0.f, 0.f, 0.f);
  const float* ob = om + (size_t)b * 256 * 512 + d0 + tx * 4;
  for (int u = 0; u < 256; ++u) {
    float4 o = *(const float4*)(ob + (size_t)u * 512);
#pragma unroll
    for (int j = 0; j < 8; ++j) {
      float w = wm[(ty * 8 + j) * TR_LDW + u];
      acc[j].x += o.x * w;
      acc[j].y += o.y * w;
      acc[j].z += o.z * w;
      acc[j].w += o.w * w;
    }
  }
#pragma unroll
  for (int j = 0; j < 8; ++j) {
    const int t = ty * 8 + j;
    const float inv = s_inv[t];
    float4 r;
    r.x = acc[j].x * inv;
    r.y = acc[j].y * inv;
    r.z = acc[j].z * inv;
    r.w = acc[j].w * inv;
    *(float4*)(tgtR + ((size_t)(b * 256 + t0 + t)) * 512 + d0 + tx * 4) = r;
  }
}

// ---------------- stage 2b: row squared norms ----------------
__global__ __launch_bounds__(256) void k_rowsq(const float* __restrict__ X,
                                               float* __restrict__ sq) {
  const int r = blockIdx.x;
  const int tid = threadIdx.x;
  float2 v = *(const float2*)(X + (size_t)r * 512 + 2 * tid);
  float s = v.x * v.x + v.y * v.y;
  s = block_reduce_sum_256(s);
  if (tid == 0) sq[r] = s;
}

// ---------------- stage 2c: hi/lo bf16 split ----------------
__device__ __forceinline__ unsigned short bf16_rne(float f) {
  unsigned int u = __float_as_uint(f);
  u += 0x7fffu + ((u >> 16) & 1u);
  return (unsigned short)(u >> 16);
}

__global__ __launch_bounds__(256) void k_split(const float* __restrict__ tgtR,
                                               const float* __restrict__ srcR,
                                               unsigned short* __restrict__ Ahi,
                                               unsigned short* __restrict__ Alo,
                                               unsigned short* __restrict__ Bhi,
                                               unsigned short* __restrict__ Blo) {
  const int NT = 8192 * 512 / 4;
  const int NS = 4096 * 512 / 4;
  const int total = NT + NS;
  for (int idx = blockIdx.x * 256 + threadIdx.x; idx < total; idx += gridDim.x * 256) {
    const float* src;
    unsigned short *hi, *lo;
    int i;
    if (idx < NT) {
      src = tgtR; hi = Ahi; lo = Alo; i = idx;
    } else {
      src = srcR; hi = Bhi; lo = Blo; i = idx - NT;
    }
    float4 v = *(const float4*)(src + (size_t)i * 4);
    ushort4 h, l;
    float x, hf;
    x = v.x; h.x = bf16_rne(x); hf = __uint_as_float((unsigned int)h.x << 16); l.x = bf16_rne(x - hf);
    x = v.y; h.y = bf16_rne(x); hf = __uint_as_float((unsigned int)h.y << 16); l.y = bf16_rne(x - hf);
    x = v.z; h.z = bf16_rne(x); hf = __uint_as_float((unsigned int)h.z << 16); l.z = bf16_rne(x - hf);
    x = v.w; h.w = bf16_rne(x); hf = __uint_as_float((unsigned int)h.w << 16); l.w = bf16_rne(x - hf);
    *(ushort4*)(hi + (size_t)i * 4) = h;
    *(ushort4*)(lo + (size_t)i * 4) = l;
  }
}

// ---------------- stage 3: cross GEMM (bf16 MFMA, split-fp32) + dist + exp ----------------
// C[M=8192, N=4096], virtual K = 3*512 (hi.hi + hi.lo + lo.hi).
// 128x128 tile, BK=32, 4 waves, each wave 64x64 (4x4 fragments of 16x16x32).
// LDS in fragment order: block b (16 rows), lane l -> row (l&15), k 8*(l>>4)..+7; 16B/lane.
__global__ __launch_bounds__(256) void k_cross_mfma(
    const unsigned short* __restrict__ Ahi, const unsigned short* __restrict__ Alo,
    const unsigned short* __restrict__ Bhi, const unsigned short* __restrict__ Blo,
    const float* __restrict__ tsq, const float* __restrict__ ssq,
    float* __restrict__ out) {
  __shared__ unsigned short As[128 * 32];
  __shared__ unsigned short Bs[128 * 32];
  const int tid = threadIdx.x;
  const int lane = tid & 63, w = tid >> 6;
  const int wm = w >> 1, wn = w & 1;
  const int row0 = blockIdx.y * 128, col0 = blockIdx.x * 128;

  f32x4 acc[4][4];
#pragma unroll
  for (int i = 0; i < 4; ++i)
#pragma unroll
    for (int j = 0; j < 4; ++j) acc[i][j] = (f32x4){0.f, 0.f, 0.f, 0.f};

  const int lr = lane & 15, lkw = (lane >> 4) * 8;
  const size_t aoff0 = (size_t)(row0 + (w * 2) * 16 + lr) * 512 + lkw;
  const size_t aoff1 = aoff0 + 16 * 512;
  const size_t boff0 = (size_t)(col0 + (w * 2) * 16 + lr) * 512 + lkw;
  const size_t boff1 = boff0 + 16 * 512;
  unsigned short* ldsA0 = As + (w * 2) * 512;
  unsigned short* ldsA1 = As + (w * 2 + 1) * 512;
  unsigned short* ldsB0 = Bs + (w * 2) * 512;
  unsigned short* ldsB1 = Bs + (w * 2 + 1) * 512;

  for (int seg = 0; seg < 3; ++seg) {
    const unsigned short* Ap = (seg == 2) ? Alo : Ahi;
    const unsigned short* Bp = (seg == 1) ? Blo : Bhi;
    for (int kt = 0; kt < 16; ++kt) {
      const int kb = kt * 32;
      __syncthreads();  // previous iteration's ds_reads done before overwrite
      gload_lds16(Ap + aoff0 + kb, ldsA0);
      gload_lds16(Ap + aoff1 + kb, ldsA1);
      gload_lds16(Bp + boff0 + kb, ldsB0);
      gload_lds16(Bp + boff1 + kb, ldsB1);
      __syncthreads();  // staging complete (compiler drains vmcnt before barrier)
      bf16x8 af[4], bfr[4];
#pragma unroll
      for (int i = 0; i < 4; ++i) {
        af[i] = *(const bf16x8*)(As + ((wm * 4 + i) * 64 + lane) * 8);
        bfr[i] = *(const bf16x8*)(Bs + ((wn * 4 + i) * 64 + lane) * 8);
      }
#pragma unroll
      for (int i = 0; i < 4; ++i)
#pragma unroll
        for (int j = 0; j < 4; ++j)
          acc[i][j] = __builtin_amdgcn_mfma_f32_16x16x32_bf16(af[i], bfr[j], acc[i][j], 0, 0, 0);
    }
  }

  // epilogue: d2 = t2 + s2 - 2c ; out = exp(-sqrt(max(d2,eps)))
  // C/D layout: col = lane&15, row = (lane>>4)*4 + reg  [m89-verified]
  const int cbase = col0 + wn * 64 + (lane & 15);
  const int rbase = row0 + wm * 64 + (lane >> 4) * 4;
  float ss[4];
#pragma unroll
  for (int j = 0; j < 4; ++j) ss[j] = ssq[cbase + j * 16];
#pragma unroll
  for (int i = 0; i < 4; ++i) {
#pragma unroll
    for (int r = 0; r < 4; ++r) {
      const int row = rbase + i * 16 + r;
      const float t2 = tsq[row];
      float* op = out + (size_t)row * 4096 + cbase;
#pragma unroll
      for (int j = 0; j < 4; ++j) {
        float d2 = t2 + ss[j] - 2.0f * acc[i][j][r];
        op[j * 16] = expf(-sqrtf(fmaxf(d2, EPSF)));
      }
    }
  }
}

// ---------------- stage 4: row L1 normalize ----------------
__global__ __launch_bounds__(256) void k_norm(float* __restrict__ out) {
  const size_t base = (size_t)blockIdx.x * 4096;
  const int tid = threadIdx.x;
  float4 v[4];
  float s = 0.f;
#pragma unroll
  for (int i = 0; i < 4; ++i) {
    v[i] = *(const float4*)(out + base + (size_t)(tid + 256 * i) * 4);
    s += v[i].x + v[i].y + v[i].z + v[i].w;
  }
  s = block_reduce_sum_256(s);
  const float inv = 1.0f / fmaxf(s, EPSF);
#pragma unroll
  for (int i = 0; i < 4; ++i) {
    float4 r;
    r.x = v[i].x * inv;
    r.y = v[i].y * inv;
    r.z = v[i].z * inv;
    r.w = v[i].w * inv;
    *(float4*)(out + base + (size_t)(tid + 256 * i) * 4) = r;
  }
}

extern "C" void kernel_launch(void* const* d_in, const int* in_sizes, int n_in,
                              void* d_out, int out_size, void* d_ws, size_t ws_size,
                              hipStream_t stream) {
  const float* m = (const float*)d_in[0];        // [4096,32,512]
  const float* om = (const float*)d_in[1];       // [32,256,512]
  const int* src_mask = (const int*)d_in[2];     // [4096,1,32]
  const int* tgt_mask = (const int*)d_in[3];     // [32,256,256]
  float* out = (float*)d_out;                    // [32,256,4096]

  float* ws = (float*)d_ws;
  float* srcR = ws;                          // 4096*512 f32
  float* tgtR = srcR + 4096 * 512;           // 8192*512 f32
  float* ssq = tgtR + 8192 * 512;            // 4096
  float* tsq = ssq + 4096;                   // 8192
  unsigned short* Ahi = (unsigned short*)(tsq + 8192);  // 8192*512 bf16
  unsigned short* Alo = Ahi + 8192 * 512;
  unsigned short* Bhi = Alo + 8192 * 512;    // 4096*512 bf16
  unsigned short* Blo = Bhi + 4096 * 512;

  k_src_readout<<<4096, 256, 0, stream>>>(m, src_mask, srcR);
  k_tgt_readout<<<dim3(32, 4, 4), 256, 0, stream>>>(om, tgt_mask, tgtR);
  k_rowsq<<<4096, 256, 0, stream>>>(srcR, ssq);
  k_rowsq<<<8192, 256, 0, stream>>>(tgtR, tsq);
  k_split<<<2048, 256, 0, stream>>>(tgtR, srcR, Ahi, Alo, Bhi, Blo);
  k_cross_mfma<<<dim3(32, 64), 256, 0, stream>>>(Ahi, Alo, Bhi, Blo, tsq, ssq, out);
  k_norm<<<8192, 256, 0, stream>>>(out);
}

// Round 3
// 208.824 us; speedup vs baseline: 2.5276x; 1.6819x over previous
//
#include <hip/hip_runtime.h>
#include <math.h>

#define EPSF 1e-12f

typedef short bf16x8 __attribute__((ext_vector_type(8)));
typedef float f32x4 __attribute__((ext_vector_type(4)));

__device__ __forceinline__ void gload_lds16(const void* g, void* l) {
  __builtin_amdgcn_global_load_lds(
      (const __attribute__((address_space(1))) unsigned int*)g,
      (__attribute__((address_space(3))) unsigned int*)l, 16, 0, 0);
}

__device__ __forceinline__ unsigned short bf16_rne(float f) {
  unsigned int u = __float_as_uint(f);
  u += 0x7fffu + ((u >> 16) & 1u);
  return (unsigned short)(u >> 16);
}

__device__ __forceinline__ float bf16_to_f32(unsigned short h) {
  return __uint_as_float((unsigned int)h << 16);
}

// ---------------- block reduce (256 threads, wave64) ----------------
__device__ __forceinline__ float block_reduce_sum_256(float v) {
#pragma unroll
  for (int o = 32; o > 0; o >>= 1) v += __shfl_down(v, o, 64);
  __shared__ float ws4[4];
  const int lane = threadIdx.x & 63;
  const int w = threadIdx.x >> 6;
  if (lane == 0) ws4[w] = v;
  __syncthreads();
  if (threadIdx.x == 0) ws4[0] = ws4[0] + ws4[1] + ws4[2] + ws4[3];
  __syncthreads();
  return ws4[0];
}

// ---------------- stage 1: src readout -> bf16 [4096,512] + row sq-norm ----------------
__global__ __launch_bounds__(256) void k_src_readout(const float* __restrict__ m,
                                                     const int* __restrict__ src_mask,
                                                     unsigned short* __restrict__ srcRb,
                                                     float* __restrict__ ssq) {
  const int b = blockIdx.x;
  __shared__ int msk[32];
  __shared__ float s_inv;
  const int tid = threadIdx.x;
  if (tid < 32) msk[tid] = src_mask[b * 32 + tid];
  __syncthreads();
  if (tid == 0) {
    float c = 0.f;
    for (int s = 0; s < 32; ++s) c += (float)msk[s];
    s_inv = 1.0f / fmaxf(c, EPSF);
  }
  __syncthreads();
  const float inv = s_inv;
  const float* mb = m + (size_t)b * (32 * 512) + 2 * tid;
  float ax = 0.f, ay = 0.f;
  for (int s = 0; s < 32; ++s) {
    if (msk[s] != 0) {
      float2 v = *(const float2*)(mb + s * 512);
      ax += v.x;
      ay += v.y;
    }
  }
  ushort2 o;
  o.x = bf16_rne(ax * inv);
  o.y = bf16_rne(ay * inv);
  *(ushort2*)(srcRb + (size_t)b * 512 + 2 * tid) = o;
  // squared norm of the bf16-rounded readout (so d2 == ||t~ - s~||^2 exactly)
  float fx = bf16_to_f32(o.x), fy = bf16_to_f32(o.y);
  float s = fx * fx + fy * fy;
  s = block_reduce_sum_256(s);
  if (tid == 0) ssq[b] = s;
}

// ---------------- stage 2: tgt readout -> bf16 [8192,512] ----------------
#define TR_LDW 257
__global__ __launch_bounds__(256) void k_tgt_readout(const float* __restrict__ om,
                                                     const int* __restrict__ tgt_mask,
                                                     unsigned short* __restrict__ tgtRb) {
  const int b = blockIdx.x, tt = blockIdx.y, dt = blockIdx.z;
  const int t0 = tt * 64, d0 = dt * 128;
  __shared__ float wm[64 * TR_LDW];
  __shared__ float cpart[256];
  __shared__ float s_inv[64];
  const int tid = threadIdx.x;
  const int* mbase = tgt_mask + ((size_t)(b * 256 + t0)) * 256;
  for (int i = 0; i < 64; ++i) {
    int idx = tid + 256 * i;
    wm[(idx >> 8) * TR_LDW + (idx & 255)] = (float)mbase[idx];
  }
  __syncthreads();
  {
    const int r = tid >> 2, q = tid & 3;
    float c = 0.f;
    for (int u = 0; u < 64; ++u) c += wm[r * TR_LDW + q * 64 + u];
    cpart[tid] = c;
  }
  __syncthreads();
  if (tid < 64) {
    float c = cpart[4 * tid] + cpart[4 * tid + 1] + cpart[4 * tid + 2] + cpart[4 * tid + 3];
    s_inv[tid] = 1.0f / fmaxf(c, EPSF);
  }
  __syncthreads();
  const int tx = tid & 31, ty = tid >> 5;
  float4 acc[8];
#pragma unroll
  for (int j = 0; j < 8; ++j) acc[j] = make_float4(0.f, 0.f, 0.f, 0.f);
  const float* ob = om + (size_t)b * 256 * 512 + d0 + tx * 4;
  for (int u = 0; u < 256; ++u) {
    float4 o = *(const float4*)(ob + (size_t)u * 512);
#pragma unroll
    for (int j = 0; j < 8; ++j) {
      float w = wm[(ty * 8 + j) * TR_LDW + u];
      acc[j].x += o.x * w;
      acc[j].y += o.y * w;
      acc[j].z += o.z * w;
      acc[j].w += o.w * w;
    }
  }
#pragma unroll
  for (int j = 0; j < 8; ++j) {
    const int t = ty * 8 + j;
    const float inv = s_inv[t];
    ushort4 r;
    r.x = bf16_rne(acc[j].x * inv);
    r.y = bf16_rne(acc[j].y * inv);
    r.z = bf16_rne(acc[j].z * inv);
    r.w = bf16_rne(acc[j].w * inv);
    *(ushort4*)(tgtRb + ((size_t)(b * 256 + t0 + t)) * 512 + d0 + tx * 4) = r;
  }
}

// ---------------- stage 2b: row squared norms from bf16 ----------------
__global__ __launch_bounds__(256) void k_rowsq_bf16(const unsigned short* __restrict__ X,
                                                    float* __restrict__ sq) {
  const int r = blockIdx.x;
  const int tid = threadIdx.x;
  ushort2 v = *(const ushort2*)(X + (size_t)r * 512 + 2 * tid);
  float fx = bf16_to_f32(v.x), fy = bf16_to_f32(v.y);
  float s = fx * fx + fy * fy;
  s = block_reduce_sum_256(s);
  if (tid == 0) sq[r] = s;
}

// ---------------- stage 3: cross GEMM (bf16 MFMA) + dist + exp ----------------
// C[M=8192, N=4096], K=512. 128x128 tile, BK=32, 4 waves, wave = 64x64 (4x4 x 16x16x32).
// LDS fragment order: 16-row block b, lane l -> row (l&15), k (l>>4)*8..+7 ; 16B/lane.
__global__ __launch_bounds__(256) void k_cross_mfma(
    const unsigned short* __restrict__ A, const unsigned short* __restrict__ B,
    const float* __restrict__ tsq, const float* __restrict__ ssq,
    float* __restrict__ out) {
  __shared__ unsigned short As[128 * 32];
  __shared__ unsigned short Bs[128 * 32];
  const int tid = threadIdx.x;
  const int lane = tid & 63, w = tid >> 6;
  const int wm = w >> 1, wn = w & 1;
  const int row0 = blockIdx.y * 128, col0 = blockIdx.x * 128;

  f32x4 acc[4][4];
#pragma unroll
  for (int i = 0; i < 4; ++i)
#pragma unroll
    for (int j = 0; j < 4; ++j) acc[i][j] = (f32x4){0.f, 0.f, 0.f, 0.f};

  const int lr = lane & 15, lkw = (lane >> 4) * 8;
  const size_t aoff0 = (size_t)(row0 + (w * 2) * 16 + lr) * 512 + lkw;
  const size_t aoff1 = aoff0 + 16 * 512;
  const size_t boff0 = (size_t)(col0 + (w * 2) * 16 + lr) * 512 + lkw;
  const size_t boff1 = boff0 + 16 * 512;
  unsigned short* ldsA0 = As + (w * 2) * 512;
  unsigned short* ldsA1 = As + (w * 2 + 1) * 512;
  unsigned short* ldsB0 = Bs + (w * 2) * 512;
  unsigned short* ldsB1 = Bs + (w * 2 + 1) * 512;

  for (int kt = 0; kt < 16; ++kt) {
    const int kb = kt * 32;
    __syncthreads();  // previous iteration's ds_reads done before overwrite
    gload_lds16(A + aoff0 + kb, ldsA0);
    gload_lds16(A + aoff1 + kb, ldsA1);
    gload_lds16(B + boff0 + kb, ldsB0);
    gload_lds16(B + boff1 + kb, ldsB1);
    __syncthreads();  // staging complete (compiler drains vmcnt before barrier)
    bf16x8 af[4], bfr[4];
#pragma unroll
    for (int i = 0; i < 4; ++i) {
      af[i] = *(const bf16x8*)(As + ((wm * 4 + i) * 64 + lane) * 8);
      bfr[i] = *(const bf16x8*)(Bs + ((wn * 4 + i) * 64 + lane) * 8);
    }
#pragma unroll
    for (int i = 0; i < 4; ++i)
#pragma unroll
      for (int j = 0; j < 4; ++j)
        acc[i][j] = __builtin_amdgcn_mfma_f32_16x16x32_bf16(af[i], bfr[j], acc[i][j], 0, 0, 0);
  }

  // epilogue: d2 = t2 + s2 - 2c ; out = exp(-sqrt(max(d2,eps)))
  // C/D layout: col = lane&15, row = (lane>>4)*4 + reg  [m89-verified]
  const int cbase = col0 + wn * 64 + (lane & 15);
  const int rbase = row0 + wm * 64 + (lane >> 4) * 4;
  float ss[4];
#pragma unroll
  for (int j = 0; j < 4; ++j) ss[j] = ssq[cbase + j * 16];
#pragma unroll
  for (int i = 0; i < 4; ++i) {
#pragma unroll
    for (int r = 0; r < 4; ++r) {
      const int row = rbase + i * 16 + r;
      const float t2 = tsq[row];
      float* op = out + (size_t)row * 4096 + cbase;
#pragma unroll
      for (int j = 0; j < 4; ++j) {
        float d2 = t2 + ss[j] - 2.0f * acc[i][j][r];
        op[j * 16] = expf(-sqrtf(fmaxf(d2, EPSF)));
      }
    }
  }
}

// ---------------- stage 4: row L1 normalize ----------------
__global__ __launch_bounds__(256) void k_norm(float* __restrict__ out) {
  const size_t base = (size_t)blockIdx.x * 4096;
  const int tid = threadIdx.x;
  float4 v[4];
  float s = 0.f;
#pragma unroll
  for (int i = 0; i < 4; ++i) {
    v[i] = *(const float4*)(out + base + (size_t)(tid + 256 * i) * 4);
    s += v[i].x + v[i].y + v[i].z + v[i].w;
  }
  s = block_reduce_sum_256(s);
  const float inv = 1.0f / fmaxf(s, EPSF);
#pragma unroll
  for (int i = 0; i < 4; ++i) {
    float4 r;
    r.x = v[i].x * inv;
    r.y = v[i].y * inv;
    r.z = v[i].z * inv;
    r.w = v[i].w * inv;
    *(float4*)(out + base + (size_t)(tid + 256 * i) * 4) = r;
  }
}

extern "C" void kernel_launch(void* const* d_in, const int* in_sizes, int n_in,
                              void* d_out, int out_size, void* d_ws, size_t ws_size,
                              hipStream_t stream) {
  const float* m = (const float*)d_in[0];        // [4096,32,512]
  const float* om = (const float*)d_in[1];       // [32,256,512]
  const int* src_mask = (const int*)d_in[2];     // [4096,1,32]
  const int* tgt_mask = (const int*)d_in[3];     // [32,256,256]
  float* out = (float*)d_out;                    // [32,256,4096]

  float* ws = (float*)d_ws;
  float* ssq = ws;                                   // 4096 f32
  float* tsq = ssq + 4096;                           // 8192 f32
  unsigned short* srcRb = (unsigned short*)(tsq + 8192);  // 4096*512 bf16
  unsigned short* tgtRb = srcRb + 4096 * 512;             // 8192*512 bf16

  k_src_readout<<<4096, 256, 0, stream>>>(m, src_mask, srcRb, ssq);
  k_tgt_readout<<<dim3(32, 4, 4), 256, 0, stream>>>(om, tgt_mask, tgtRb);
  k_rowsq_bf16<<<8192, 256, 0, stream>>>(tgtRb, tsq);
  k_cross_mfma<<<dim3(32, 64), 256, 0, stream>>>(tgtRb, srcRb, tsq, ssq, out);
  k_norm<<<8192, 256, 0, stream>>>(out);
}